// Round 7
// baseline (570.894 us; speedup 1.0000x reference)
//
#include <hip/hip_runtime.h>
#include <math.h>

#define BB 64
#define NN 1024
#define CC 50
#define HH 512
#define KK 10
#define DP 64        // padded channel count for MFMA (d in [50,64) zeroed / discarded)
#define H1S 52       // h1s row stride (16B-aligned, float4-readable)

typedef short bf16x8 __attribute__((ext_vector_type(8)));
typedef float f32x4  __attribute__((ext_vector_type(4)));

__device__ __forceinline__ float elu_f(float v) { return v > 0.f ? v : expm1f(v); }

// truncation split: f = hi + lo + eps, |eps| <= 2^-16 |f|
__device__ __forceinline__ void split_bf16(float f, unsigned short& hi, unsigned short& lo) {
    unsigned int u = __float_as_uint(f);
    hi = (unsigned short)(u >> 16);
    float hif = __uint_as_float(u & 0xFFFF0000u);
    lo = (unsigned short)(__float_as_uint(f - hif) >> 16);
}

// --------------------------------------------------------------------------
// K1: 16 blocks/batch, each owns 64 node rows. Four phases:
//  P1 s-dot:  s[n] = A[b,n,:] . x[b]     (one row/wave/iter; x held in 4
//             float4 REGISTERS per lane -- loop-invariant)
//  P2 h1:     h1[n][c] = elu(s[n]*w1[c]+b1[c])   (full 256-thread parallel)
//  P3 g:      g[n][d] = sum_c h1[n][c]*w2[c][d]  (thread owns 16 contiguous n
//             at fixed d; h1 reads are wave-uniform b128 broadcasts)
//  P4 store:  split to bf16 hi/lo, TRANSPOSED Gt[b][d][n], 16B vector stores.
// d in [50,64) stores zeros (keeps K2 frag loads defined).
// Block seg==0 also zeroes pooled[b] (K2 runs strictly after K1 completes).
// --------------------------------------------------------------------------
__global__ __launch_bounds__(256) void k1_s_g(
        const float* __restrict__ x, const float* __restrict__ a,
        const float* __restrict__ w1, const float* __restrict__ b1,
        const float* __restrict__ w2,
        unsigned short* __restrict__ gt_hi, unsigned short* __restrict__ gt_lo,
        float* __restrict__ pooled)
{
    __shared__ float w1s[CC], b1s[CC];
    __shared__ float w2s[CC * CC];      // 10 KB
    __shared__ float ss[64];
    __shared__ float h1s[64 * H1S];     // 13.3 KB

    int tid = threadIdx.x;
    int b = blockIdx.x >> 4;            // 16 blocks per batch
    int seg = blockIdx.x & 15;
    int n0 = seg * 64;                  // rows [n0, n0+64)
    int wid = tid >> 6, lane = tid & 63;

    if (seg == 0 && tid < CC) pooled[b * CC + tid] = 0.f;
    if (tid < CC) { w1s[tid] = w1[tid]; b1s[tid] = b1[tid]; }
    for (int i = tid; i < CC * CC; i += 256) w2s[i] = w2[i];

    // x[b] hoisted into registers: lane's 4 float4 slices (loop-invariant)
    float4 xv[4];
    {
        const float4* xb4 = (const float4*)(x + (size_t)b * NN);
        #pragma unroll
        for (int k4 = 0; k4 < 4; ++k4) xv[k4] = xb4[k4 * 64 + lane];
    }
    __syncthreads();

    // ---- P1: s-dot, one row per wave per iteration (16 iters x 4 waves) ----
    for (int it = 0; it < 16; ++it) {
        int nl = it * 4 + wid;
        const float4* arow = (const float4*)(a + ((size_t)b * NN + n0 + nl) * NN);
        float acc = 0.f;
        #pragma unroll
        for (int k4 = 0; k4 < 4; ++k4) {
            float4 av = arow[k4 * 64 + lane];
            acc += av.x * xv[k4].x + av.y * xv[k4].y + av.z * xv[k4].z + av.w * xv[k4].w;
        }
        #pragma unroll
        for (int off = 32; off; off >>= 1) acc += __shfl_xor(acc, off);
        if (lane == 0) ss[nl] = acc;
    }
    __syncthreads();

    // ---- P2: h1 (64 n x 50 c, fully parallel) ----
    {
        int c = tid & 63, nb = tid >> 6;
        if (c < CC) {
            float w1c = w1s[c], b1c = b1s[c];
            #pragma unroll
            for (int it = 0; it < 16; ++it) {
                int nl = it * 4 + nb;
                h1s[nl * H1S + c] = elu_f(ss[nl] * w1c + b1c);
            }
        }
    }
    __syncthreads();

    // ---- P3+P4: g = h1 @ w2, thread owns (d = tid&63, n-chunk nb*16..+16) ----
    {
        int d = tid & 63, nb = tid >> 6;
        float accg[16] = {};
        if (d < CC) {
            const float* h1base = &h1s[(size_t)nb * 16 * H1S];
            for (int cq = 0; cq < 48; cq += 4) {
                float w2q0 = w2s[(cq + 0) * CC + d];
                float w2q1 = w2s[(cq + 1) * CC + d];
                float w2q2 = w2s[(cq + 2) * CC + d];
                float w2q3 = w2s[(cq + 3) * CC + d];
                #pragma unroll
                for (int it = 0; it < 16; ++it) {
                    float4 h4 = *(const float4*)(h1base + it * H1S + cq);  // wave-uniform broadcast
                    accg[it] += h4.x * w2q0 + h4.y * w2q1 + h4.z * w2q2 + h4.w * w2q3;
                }
            }
            #pragma unroll
            for (int c = 48; c < CC; ++c) {
                float w2v = w2s[c * CC + d];
                #pragma unroll
                for (int it = 0; it < 16; ++it)
                    accg[it] += h1base[it * H1S + c] * w2v;
            }
        }
        // split + pack + 16B stores (Gt[b][d][n0 + nb*16 .. +16))
        bf16x8 h0, h1v, l0, l1;
        #pragma unroll
        for (int j = 0; j < 8; ++j) {
            unsigned short hi, lo;
            split_bf16(accg[j], hi, lo);      h0[j] = (short)hi; l0[j] = (short)lo;
            split_bf16(accg[8 + j], hi, lo);  h1v[j] = (short)hi; l1[j] = (short)lo;
        }
        size_t off = ((size_t)b * DP + d) * NN + n0 + nb * 16;
        *(bf16x8*)(gt_hi + off)     = h0;
        *(bf16x8*)(gt_hi + off + 8) = h1v;
        *(bf16x8*)(gt_lo + off)     = l0;
        *(bf16x8*)(gt_lo + off + 8) = l1;
    }
}

// --------------------------------------------------------------------------
// K2 (MFMA): t[n,d] = sum_m A[b,n,m]*g[b,m,d] via split-bf16 (3 products,
// fp32 accumulate, rel err ~2^-15); pooled[b,d] += sum_n elu(t + b2[d]).
// Grid 1024 = 16 blocks/batch (4 blocks/CU -> 16 waves/CU for latency hiding).
// Wave owns 16 n x 64 d: 12 MFMA + 10 VMEM per k-step, 32 k-steps, unroll 2.
// A-fragments direct global->register (zero reuse; A ~95% L3-resident since
// both grids are fully co-resident and A=268MB vs 256MB LLC).
// B-fragments: 16B loads from Gt (L2-hot, 256KB/batch).
// Fragment layouts hardware-verified (r3 kernel passed, absmax 0.0):
//   A: lane l holds A[l&15][8*(l>>4)+j]   B: lane l holds B[8*(l>>4)+j][l&15]
//   D: lane l holds D[4*(l>>4)+j][l&15]
// --------------------------------------------------------------------------
__global__ __launch_bounds__(256) void k2_mfma_pool(
        const float* __restrict__ a,
        const unsigned short* __restrict__ gt_hi,
        const unsigned short* __restrict__ gt_lo,
        const float* __restrict__ b2, float* __restrict__ pooled)
{
    __shared__ float ps[DP];

    int tid = threadIdx.x;
    int wv = tid >> 6, l = tid & 63;
    int lr = l & 15, lk = l >> 4;
    int b  = (BB - 1) - (blockIdx.x >> 4);     // reverse order (free; likely moot)
    int n0 = (blockIdx.x & 15) * 64 + wv * 16; // this wave's 16 rows

    const float* Ab = a + ((size_t)b * NN + n0) * NN;
    const unsigned short* Gh = gt_hi + (size_t)b * DP * NN;
    const unsigned short* Gl = gt_lo + (size_t)b * DP * NN;

    if (tid < DP) ps[tid] = 0.f;
    __syncthreads();

    float bias[4];
    #pragma unroll
    for (int ds = 0; ds < 4; ++ds) {
        int d = ds * 16 + lr;
        bias[ds] = (d < CC) ? b2[d] : 0.f;
    }

    f32x4 acc[4] = {};   // 4 d-subtiles for this wave's 16 rows

    #pragma unroll 2
    for (int m0 = 0; m0 < NN; m0 += 32) {
        // A fragment: lane holds A[n0+lr][m0+lk*8 .. +8], split hi/lo in-register
        bf16x8 ah, al;
        {
            const float* ap = Ab + (size_t)lr * NN + m0 + lk * 8;
            float4 v0 = *(const float4*)(ap);
            float4 v1 = *(const float4*)(ap + 4);
            float av[8] = {v0.x, v0.y, v0.z, v0.w, v1.x, v1.y, v1.z, v1.w};
            #pragma unroll
            for (int j = 0; j < 8; ++j) {
                unsigned short hi, lo;
                split_bf16(av[j], hi, lo);
                ah[j] = (short)hi;
                al[j] = (short)lo;
            }
        }
        // B fragments: Gt[d][m], 8 contiguous bf16 = one 16B load
        bf16x8 bh[4], bl[4];
        #pragma unroll
        for (int ds = 0; ds < 4; ++ds) {
            size_t off = (size_t)(ds * 16 + lr) * NN + m0 + lk * 8;
            bh[ds] = *(const bf16x8*)(Gh + off);
            bl[ds] = *(const bf16x8*)(Gl + off);
        }
        // 3-product split MFMA
        #pragma unroll
        for (int ds = 0; ds < 4; ++ds) {
            acc[ds] = __builtin_amdgcn_mfma_f32_16x16x32_bf16(ah, bh[ds], acc[ds], 0, 0, 0);
            acc[ds] = __builtin_amdgcn_mfma_f32_16x16x32_bf16(ah, bl[ds], acc[ds], 0, 0, 0);
            acc[ds] = __builtin_amdgcn_mfma_f32_16x16x32_bf16(al, bh[ds], acc[ds], 0, 0, 0);
        }
    }

    // epilogue: elu(t + b2); lane holds D[4*lk+j][lr]; sum j then lk-groups
    #pragma unroll
    for (int ds = 0; ds < 4; ++ds) {
        int d = ds * 16 + lr;
        float s = 0.f;
        if (d < CC) {
            #pragma unroll
            for (int j = 0; j < 4; ++j)
                s += elu_f(acc[ds][j] + bias[ds]);
        }
        s += __shfl_xor(s, 16);
        s += __shfl_xor(s, 32);
        if (lk == 0 && d < CC) atomicAdd(&ps[d], s);
    }
    __syncthreads();
    if (tid < CC) atomicAdd(&pooled[b * CC + tid], ps[tid]);
}

// --------------------------------------------------------------------------
// K3: pooled[b,:] -> relu(fc1) -> softmax(fc2). One block per batch row.
// --------------------------------------------------------------------------
__global__ __launch_bounds__(256) void k3_fc(
        const float* __restrict__ pooled,
        const float* __restrict__ wf1, const float* __restrict__ bf1,
        const float* __restrict__ wf2, const float* __restrict__ bf2,
        float* __restrict__ out)
{
    __shared__ float p[CC];
    __shared__ float h[HH];
    __shared__ float lg[KK];
    int b = blockIdx.x, tid = threadIdx.x;

    if (tid < CC) p[tid] = pooled[b * CC + tid];
    __syncthreads();

    for (int j = tid; j < HH; j += 256) {
        float acc = bf1[j];
        #pragma unroll 10
        for (int c = 0; c < CC; ++c) acc += p[c] * wf1[c * HH + j];
        h[j] = fmaxf(acc, 0.f);
    }
    __syncthreads();

    if (tid < KK) {
        float acc = bf2[tid];
        for (int j = 0; j < HH; ++j) acc += h[j] * wf2[j * KK + tid];
        lg[tid] = acc;
    }
    __syncthreads();

    if (tid == 0) {
        float mx = lg[0];
        for (int k = 1; k < KK; ++k) mx = fmaxf(mx, lg[k]);
        float e[KK], sum = 0.f;
        for (int k = 0; k < KK; ++k) { e[k] = expf(lg[k] - mx); sum += e[k]; }
        float inv = 1.f / sum;
        for (int k = 0; k < KK; ++k) out[b * KK + k] = e[k] * inv;
    }
}

extern "C" void kernel_launch(void* const* d_in, const int* in_sizes, int n_in,
                              void* d_out, int out_size, void* d_ws, size_t ws_size,
                              hipStream_t stream) {
    const float* x   = (const float*)d_in[0];
    const float* a   = (const float*)d_in[1];
    const float* w1  = (const float*)d_in[2];
    const float* b1  = (const float*)d_in[3];
    const float* w2  = (const float*)d_in[4];
    const float* b2  = (const float*)d_in[5];
    const float* wf1 = (const float*)d_in[6];
    const float* bf1 = (const float*)d_in[7];
    const float* wf2 = (const float*)d_in[8];
    const float* bf2 = (const float*)d_in[9];
    float* out = (float*)d_out;

    // workspace: [0,64KB) pooled | [64KB,+8MB) gt_hi | [+8MB,+8MB) gt_lo
    float*          pooled = (float*)d_ws;
    unsigned short* gt_hi  = (unsigned short*)((char*)d_ws + (64 << 10));
    unsigned short* gt_lo  = (unsigned short*)((char*)d_ws + (64 << 10) + ((size_t)BB * DP * NN * 2));

    k1_s_g<<<BB * 16, 256, 0, stream>>>(x, a, w1, b1, w2, gt_hi, gt_lo, pooled);
    k2_mfma_pool<<<BB * 16, 256, 0, stream>>>(a, gt_hi, gt_lo, b2, pooled);
    k3_fc<<<BB, 256, 0, stream>>>(pooled, wf1, bf1, wf2, bf2, out);
}